// Round 7
// baseline (833.928 us; speedup 1.0000x reference)
//
#include <hip/hip_runtime.h>
#include <hip/hip_bf16.h>
#include <type_traits>

// Problem constants
#define Bb  2
#define Ss  2048
#define Hh  2048
#define NHh 16
#define HDd 128
#define Mm  (Bb * Ss)   // 4096 rows

typedef __attribute__((ext_vector_type(8))) short short8;  // 8 bf16 (4 VGPRs)
typedef __attribute__((ext_vector_type(4))) float f32x4;   // MFMA accumulator

#if __has_builtin(__builtin_amdgcn_exp2f)
#define EXPFN(x) __builtin_amdgcn_exp2f(x)
#define QSCALE 0.12751744416668577f   /* (1/sqrt(128)) * log2(e), folded into Q */
#else
#define EXPFN(x) __expf(x)
#define QSCALE 0.08838834764831845f   /* 1/sqrt(128) folded into Q */
#endif

__device__ __forceinline__ float bf2f(unsigned short u) {
    unsigned int x = ((unsigned int)u) << 16;
    return __builtin_bit_cast(float, x);
}
__device__ __forceinline__ unsigned short f2bf(float f) {
    unsigned int x = __builtin_bit_cast(unsigned int, f);
    x += 0x7fffu + ((x >> 16) & 1u);   // RNE
    return (unsigned short)(x >> 16);
}

// raw workgroup barrier WITHOUT the vmcnt(0)/lgkmcnt(0) drain __syncthreads() emits.
__device__ __forceinline__ void blk_barrier() {
    asm volatile("" ::: "memory");
    __builtin_amdgcn_s_barrier();
    asm volatile("" ::: "memory");
}

// ---------------------------------------------------------------- cast fp32->bf16
__global__ __launch_bounds__(256) void cast_f32_to_bf16(const float* __restrict__ in,
                                                        unsigned short* __restrict__ out, int n) {
    int i = (blockIdx.x * 256 + threadIdx.x) * 4;
    if (i + 3 < n) {
        float4 f = *(const float4*)(in + i);
        ushort4 o;
        o.x = f2bf(f.x); o.y = f2bf(f.y); o.z = f2bf(f.z); o.w = f2bf(f.w);
        *(ushort4*)(out + i) = o;
    }
}

// ---------------------------------------------------------------- GEMM: C = A * Bt^T + bias (128x128, m97)
// Used for the out-projection (N=2048 -> 512 blocks, full chip).
template <typename OutT>
__global__ __launch_bounds__(256) void gemm_bt(const unsigned short* __restrict__ A,
                                               const unsigned short* __restrict__ Bt,
                                               const float* __restrict__ bias,
                                               OutT* __restrict__ C,
                                               int M, int N, int K) {
    __shared__ unsigned short As[128 * 64];
    __shared__ unsigned short Bs[128 * 64];
    const int tid  = threadIdx.x;
    const int lane = tid & 63;
    const int wave = tid >> 6;
    const int q4 = lane >> 4, l15 = lane & 15;
    const int m0 = blockIdx.y * 128, n0 = blockIdx.x * 128;
    const int wm = (wave >> 1) * 64, wn = (wave & 1) * 64;

    f32x4 acc[4][4] = {};

    for (int k0 = 0; k0 < K; k0 += 64) {
#pragma unroll
        for (int t = 0; t < 4; ++t) {
            const int chunk = t * 256 + tid;
            const int row = chunk >> 3, c8 = chunk & 7;
            const unsigned short* ga = A  + (size_t)(m0 + row) * K + (k0 + c8 * 8);
            const unsigned short* gb = Bt + (size_t)(n0 + row) * K + (k0 + c8 * 8);
            __builtin_amdgcn_global_load_lds((const __attribute__((address_space(1))) unsigned int*)ga,
                                             (__attribute__((address_space(3))) unsigned int*)(As + chunk * 8),
                                             16, 0, 0);
            __builtin_amdgcn_global_load_lds((const __attribute__((address_space(1))) unsigned int*)gb,
                                             (__attribute__((address_space(3))) unsigned int*)(Bs + chunk * 8),
                                             16, 0, 0);
        }
        __syncthreads();
#pragma unroll
        for (int kk = 0; kk < 2; ++kk) {
            short8 a[4], b[4];
#pragma unroll
            for (int i = 0; i < 4; ++i)
                a[i] = *(const short8*)(As + (wm + i * 16 + l15) * 64 + kk * 32 + q4 * 8);
#pragma unroll
            for (int j = 0; j < 4; ++j)
                b[j] = *(const short8*)(Bs + (wn + j * 16 + l15) * 64 + kk * 32 + q4 * 8);
#pragma unroll
            for (int i = 0; i < 4; ++i)
#pragma unroll
                for (int j = 0; j < 4; ++j)
                    acc[i][j] = __builtin_amdgcn_mfma_f32_16x16x32_bf16(a[i], b[j], acc[i][j], 0, 0, 0);
        }
        __syncthreads();
    }

#pragma unroll
    for (int i = 0; i < 4; ++i) {
#pragma unroll
        for (int j = 0; j < 4; ++j) {
            const int col = n0 + wn + j * 16 + l15;
            const float bv = bias[col];
            const size_t base = (size_t)(m0 + wm + i * 16 + q4 * 4) * N + col;
#pragma unroll
            for (int r = 0; r < 4; ++r) {
                float v = acc[i][j][r] + bv;
                if constexpr (std::is_same_v<OutT, float>)
                    C[base + (size_t)r * N] = v;
                else
                    C[base + (size_t)r * N] = f2bf(v);
            }
        }
    }
}

// ---------------------------------------------------------------- GEMM 256x256, cross-phase pipelined
// R6 post-mortem: the 8-phase schedule serialized LDS-drain and MFMA (sum, not max) ->
// 26% MfmaUtil regardless of wait placement. v7: one kk-half per phase, and the ds_reads
// for phase p+1 are ISSUED AT THE TOP of phase p, so they drain on the LDS pipe WHILE
// phase p's 32 MFMAs run from registers (no wait before MFMA at all: cur fragments were
// drained last phase). One barrier per phase (was 2). All waits counted:
//   per phase: [reads nxt<-R[(p+1)%4]] [stage kh=p+3 -> R[(p+3)%4], 4 gloads]
//              [32 MFMA on cur] [lgkmcnt(0): nxt landed (ran under MFMAs)]
//              [vmcnt(4): own stage from phase p-1 done] [barrier]
// Race ledger:
//   - read region at p was staged at p-2: every wave's vmcnt(4) at end of p-1 bounds its
//     outstanding to its p-1 stage only => all p-2 stages done; barrier(p-1) publishes.
//   - stage region at p was last LDS-read at p-2 (for p-1's MFMA): lgkmcnt(0)+barrier at
//     p-2 drained them; stage issues >= 1 barrier later. Distance 2 everywhere.
//   - prologue: stage kh0,kh1,kh2; vmcnt(4) (kh0,kh1 done); barrier; read cur<-R0.
// Register sets F0/F1 alternate with static indexing (4-phase unroll).
template <typename OutT>
__global__ __launch_bounds__(512, 2) void gemm256(const unsigned short* __restrict__ A,
                                                  const unsigned short* __restrict__ Bt,
                                                  const float* __restrict__ bias,
                                                  OutT* __restrict__ C,
                                                  int M, int N, int K) {
    __shared__ unsigned short LA[4][16][512];   // [region][seg][lane*8] 64 KB (A halves)
    __shared__ unsigned short LB[4][16][512];   // 64 KB (B halves)
    const int tid = threadIdx.x;
    const int lane = tid & 63, wave = tid >> 6;    // 8 waves
    const int q4 = lane >> 4, l15 = lane & 15;
    const int wr = wave >> 2, wc = wave & 3;       // 2x4 wave grid; per-wave 128x64 out
    const int m0 = blockIdx.y * 256, n0 = blockIdx.x * 256;
    const int NH2 = K >> 5;                        // # kk-halves (K=2048 -> 64), multiple of 4

    f32x4 acc[8][4] = {};

    // stage A-half + B-half for kk-half kh into region kh&3 (4 gload_lds/thread)
    auto stageAB = [&](int kh) {
        const int r = kh & 3;
        const int kofs = kh * 32;
#pragma unroll
        for (int it = 0; it < 2; ++it) {
            const int s = it * 8 + wave;
            const unsigned short* sa = A + (size_t)(m0 + s * 16 + l15) * K + kofs + q4 * 8;
            __builtin_amdgcn_global_load_lds((const __attribute__((address_space(1))) unsigned int*)sa,
                                             (__attribute__((address_space(3))) unsigned int*)(&LA[r][s][lane * 8]),
                                             16, 0, 0);
        }
#pragma unroll
        for (int it = 0; it < 2; ++it) {
            const int s = it * 8 + wave;
            const unsigned short* sb = Bt + (size_t)(n0 + s * 16 + l15) * K + kofs + q4 * 8;
            __builtin_amdgcn_global_load_lds((const __attribute__((address_space(1))) unsigned int*)sb,
                                             (__attribute__((address_space(3))) unsigned int*)(&LB[r][s][lane * 8]),
                                             16, 0, 0);
        }
    };

    short8 a0[8], b0f[4], a1[8], b1f[4];   // two fragment sets (static swap)

    // prologue: kh 0,1,2 staged; kh0+kh1 guaranteed; read cur(F0) <- R0
    stageAB(0); stageAB(1); stageAB(2);
    asm volatile("s_waitcnt vmcnt(4)" ::: "memory");
    blk_barrier();
#pragma unroll
    for (int m = 0; m < 8; ++m) a0[m] = *(const short8*)&LA[0][wr * 8 + m][lane * 8];
#pragma unroll
    for (int n = 0; n < 4; ++n) b0f[n] = *(const short8*)&LB[0][wc * 4 + n][lane * 8];

#define MFMA16(av, bv, cv) __builtin_amdgcn_mfma_f32_16x16x32_bf16(av, bv, cv, 0, 0, 0)

#define PHASE(ph, CA, CB, NA, NB)                                                  \
    {                                                                              \
        const int p = 4 * i + (ph);                                                \
        if (p + 1 < NH2) {                                                         \
            _Pragma("unroll")                                                      \
            for (int m = 0; m < 8; ++m)                                            \
                NA[m] = *(const short8*)&LA[((ph) + 1) & 3][wr * 8 + m][lane * 8]; \
            _Pragma("unroll")                                                      \
            for (int n = 0; n < 4; ++n)                                            \
                NB[n] = *(const short8*)&LB[((ph) + 1) & 3][wc * 4 + n][lane * 8]; \
        }                                                                          \
        if (p + 3 < NH2) stageAB(p + 3);                                           \
        __builtin_amdgcn_s_setprio(1);                                             \
        _Pragma("unroll")                                                          \
        for (int m = 0; m < 8; ++m) {                                              \
            acc[m][0] = MFMA16(CA[m], CB[0], acc[m][0]);                           \
            acc[m][1] = MFMA16(CA[m], CB[1], acc[m][1]);                           \
            acc[m][2] = MFMA16(CA[m], CB[2], acc[m][2]);                           \
            acc[m][3] = MFMA16(CA[m], CB[3], acc[m][3]);                           \
        }                                                                          \
        __builtin_amdgcn_s_setprio(0);                                             \
        asm volatile("s_waitcnt lgkmcnt(0)" ::: "memory");                         \
        asm volatile("s_waitcnt vmcnt(4)" ::: "memory");                           \
        blk_barrier();                                                             \
    }

#pragma unroll 1
    for (int i = 0; i < NH2 / 4; ++i) {
        PHASE(0, a0, b0f, a1, b1f)
        PHASE(1, a1, b1f, a0, b0f)
        PHASE(2, a0, b0f, a1, b1f)
        PHASE(3, a1, b1f, a0, b0f)
    }
#undef PHASE
#undef MFMA16

    // C/D layout: col = lane&15, row = (lane>>4)*4 + r   [m89/m91 verified]
#pragma unroll
    for (int m = 0; m < 8; ++m) {
#pragma unroll
        for (int n = 0; n < 4; ++n) {
            const int col = n0 + wc * 64 + n * 16 + l15;
            const float bv = bias[col];
            const size_t base = (size_t)(m0 + wr * 128 + m * 16 + q4 * 4) * N + col;
#pragma unroll
            for (int r = 0; r < 4; ++r) {
                float v = acc[m][n][r] + bv;
                if constexpr (std::is_same_v<OutT, float>)
                    C[base + (size_t)r * N] = v;
                else
                    C[base + (size_t)r * N] = f2bf(v);
            }
        }
    }
}

// ---------------------------------------------------------------- RoPE + repack Q,K to [B*NH][S][HD]
__global__ __launch_bounds__(256) void rope_repack(const unsigned short* __restrict__ qkv, // [B][S][3H] bf16
                                                   const float* __restrict__ cosp,         // [S][HD]
                                                   const float* __restrict__ sinp,
                                                   unsigned short* __restrict__ Qr,
                                                   unsigned short* __restrict__ Kr) {
    const int s = blockIdx.x, b = blockIdx.y, tid = threadIdx.x;
    const unsigned short* base = qkv + (size_t)(b * Ss + s) * (3 * Hh);
#pragma unroll
    for (int t = 0; t < 4; ++t) {
        const int p = t * 256 + tid;     // 0..1023 : 16 heads x 64 pairs
        const int h = p >> 6, d = p & 63;
        const float c  = cosp[s * HDd + d];
        const float sn = sinp[s * HDd + d];
        const size_t o = ((size_t)(b * NHh + h) * Ss + s) * HDd;
        float q1 = bf2f(base[h * HDd + d]), q2 = bf2f(base[h * HDd + d + 64]);
        Qr[o + d]      = f2bf((q1 * c - q2 * sn) * QSCALE);
        Qr[o + d + 64] = f2bf((q2 * c + q1 * sn) * QSCALE);
        float k1 = bf2f(base[Hh + h * HDd + d]), k2 = bf2f(base[Hh + h * HDd + d + 64]);
        Kr[o + d]      = f2bf(k1 * c - k2 * sn);
        Kr[o + d + 64] = f2bf(k2 * c + k1 * sn);
    }
}

// ---------------------------------------------------------------- V transpose: qkv V-part -> Vt [B*NH][HD][S]
__global__ __launch_bounds__(256) void v_transpose(const unsigned short* __restrict__ qkv,
                                                   unsigned short* __restrict__ Vt) {
    __shared__ unsigned short T[64 * 64];
    const int tid = threadIdx.x;
    const int st = blockIdx.x;
    const int dt = blockIdx.y;
    const int bh = blockIdx.z;
    const int b = bh >> 4, h = bh & 15;
#pragma unroll
    for (int it = 0; it < 2; ++it) {
        const int chunk = it * 256 + tid;
        const int row = chunk >> 3, c8 = chunk & 7;
        const unsigned short* src = qkv + ((size_t)(b * Ss + st * 64 + row)) * (3 * Hh)
                                        + 2 * Hh + h * HDd + dt * 64 + c8 * 8;
        uint4 v = *(const uint4*)src;
        *(uint4*)(T + row * 64 + ((c8 ^ (row & 7)) * 8)) = v;
    }
    __syncthreads();
#pragma unroll
    for (int it = 0; it < 2; ++it) {
        const int chunk = it * 256 + tid;
        const int drow = chunk & 63;
        const int c8s = chunk >> 6;
        ushort4 lo, hi;
        unsigned short tmp[8];
#pragma unroll
        for (int j = 0; j < 8; ++j) {
            const int sl = c8s * 8 + j;
            tmp[j] = T[sl * 64 + (((drow >> 3) ^ (sl & 7)) * 8) + (drow & 7)];
        }
        lo.x = tmp[0]; lo.y = tmp[1]; lo.z = tmp[2]; lo.w = tmp[3];
        hi.x = tmp[4]; hi.y = tmp[5]; hi.z = tmp[6]; hi.w = tmp[7];
        unsigned short* dst = Vt + ((size_t)bh * HDd + dt * 64 + drow) * Ss + st * 64 + c8s * 8;
        *(ushort4*)(dst)     = lo;
        *(ushort4*)(dst + 4) = hi;
    }
}

// ---------------------------------------------------------------- flash attention (causal, FA2-paired)
// 8 waves/block (512 thr): waves 0-3 own qA=blockIdx.x strips, waves 4-7 own qB=31-qA.
__global__ __launch_bounds__(512, 4) void attn_fwd(const unsigned short* __restrict__ Qr,
                                                   const unsigned short* __restrict__ Kr,
                                                   const unsigned short* __restrict__ Vt,
                                                   unsigned short* __restrict__ AO) {  // [B][S][H] bf16
    __shared__ unsigned short Ks[16 * 64 * 8];
    __shared__ unsigned short VtS[16 * 64 * 8];
    __shared__ unsigned short Ps[8][16 * 72];
    const int tid = threadIdx.x;
    const int lane = tid & 63, wave = tid >> 6;
    const int q4 = lane >> 4, l15 = lane & 15;
    const int qA = (int)blockIdx.x;
    const int qB = 31 - qA;
    const int bh = blockIdx.y;
    const int b = bh >> 4, h = bh & 15;
    const unsigned short* Qh  = Qr + (size_t)bh * Ss * HDd;
    const unsigned short* Kh  = Kr + (size_t)bh * Ss * HDd;
    const unsigned short* Vth = Vt + (size_t)bh * HDd * Ss;

    const int mt = wave >> 2;
    const int wg = wave & 3;
    const int s0 = (mt ? qB : qA) * 64 + wg * 16;

    short8 qf[4];
#pragma unroll
    for (int kc = 0; kc < 4; ++kc)
        qf[kc] = *(const short8*)(Qh + (size_t)(s0 + l15) * HDd + kc * 32 + q4 * 8);

    f32x4 o_acc[8] = {};
    float m_i[4], l_i[4];
#pragma unroll
    for (int r = 0; r < 4; ++r) { m_i[r] = -1e30f; l_i[r] = 0.f; }

    const int kv_end = qB * 64 + 64;
    for (int t0 = 0; t0 < kv_end; t0 += 64) {
#pragma unroll
        for (int it = 0; it < 2; ++it) {
            const int s = it * 8 + wave;
            const int g = s >> 2, kc = s & 3;
            const unsigned short* gk = Kh + (size_t)(t0 + g * 16 + l15) * HDd + kc * 32 + q4 * 8;
            __builtin_amdgcn_global_load_lds((const __attribute__((address_space(1))) unsigned int*)gk,
                                             (__attribute__((address_space(3))) unsigned int*)(Ks + (s * 64 + lane) * 8),
                                             16, 0, 0);
        }
#pragma unroll
        for (int it = 0; it < 2; ++it) {
            const int s = it * 8 + wave;
            const int n = s >> 1, ks = s & 1;
            const unsigned short* gv = Vth + (size_t)(n * 16 + l15) * Ss + t0 + ks * 32 + q4 * 8;
            __builtin_amdgcn_global_load_lds((const __attribute__((address_space(1))) unsigned int*)gv,
                                             (__attribute__((address_space(3))) unsigned int*)(VtS + (s * 64 + lane) * 8),
                                             16, 0, 0);
        }
        __syncthreads();

        if (t0 <= s0 + 15) {
            float sv[4][4];
#pragma unroll
            for (int g = 0; g < 4; ++g)
#pragma unroll
                for (int r = 0; r < 4; ++r) sv[g][r] = -1e30f;
#pragma unroll
            for (int g = 0; g < 4; ++g) {
                if (t0 + g * 16 <= s0 + 15) {
                    f32x4 scg = {};
#pragma unroll
                    for (int kc = 0; kc < 4; ++kc) {
                        short8 kf = *(const short8*)(Ks + ((g * 4 + kc) * 64 + lane) * 8);
                        scg = __builtin_amdgcn_mfma_f32_16x16x32_bf16(qf[kc], kf, scg, 0, 0, 0);
                    }
                    const int key = t0 + g * 16 + l15;
#pragma unroll
                    for (int r = 0; r < 4; ++r)
                        sv[g][r] = (key <= s0 + q4 * 4 + r) ? scg[r] : -1e30f;
                }
            }
            float mnew[4], alpha[4], sm[4];
            bool need = false;
#pragma unroll
            for (int r = 0; r < 4; ++r) {
                float mx = fmaxf(fmaxf(sv[0][r], sv[1][r]), fmaxf(sv[2][r], sv[3][r]));
#pragma unroll
                for (int off = 1; off < 16; off <<= 1)
                    mx = fmaxf(mx, __shfl_xor(mx, off, 16));
                mnew[r]  = fmaxf(m_i[r], mx);
                need = need || (mnew[r] > m_i[r]);
                alpha[r] = EXPFN(m_i[r] - mnew[r]);
                m_i[r] = mnew[r];
            }
            float p[4][4];
#pragma unroll
            for (int g = 0; g < 4; ++g)
#pragma unroll
                for (int r = 0; r < 4; ++r)
                    p[g][r] = EXPFN(sv[g][r] - mnew[r]);
#pragma unroll
            for (int r = 0; r < 4; ++r) {
                float s2 = (p[0][r] + p[1][r]) + (p[2][r] + p[3][r]);
#pragma unroll
                for (int off = 1; off < 16; off <<= 1)
                    s2 += __shfl_xor(s2, off, 16);
                sm[r] = s2;
            }
            if (__any(need)) {
#pragma unroll
                for (int r = 0; r < 4; ++r) l_i[r] *= alpha[r];
#pragma unroll
                for (int n = 0; n < 8; ++n)
#pragma unroll
                    for (int r = 0; r < 4; ++r)
                        o_acc[n][r] *= alpha[r];
            }
#pragma unroll
            for (int r = 0; r < 4; ++r) l_i[r] += sm[r];

            unsigned short* Pw = &Ps[wave][0];
#pragma unroll
            for (int g = 0; g < 4; ++g)
#pragma unroll
                for (int r = 0; r < 4; ++r)
                    Pw[(q4 * 4 + r) * 72 + g * 16 + l15] = f2bf(p[g][r]);

#pragma unroll
            for (int ks = 0; ks < 2; ++ks) {
                if (t0 + ks * 32 <= s0 + 15) {
                    short8 pfk = *(const short8*)(Pw + l15 * 72 + ks * 32 + q4 * 8);
#pragma unroll
                    for (int n = 0; n < 8; ++n) {
                        short8 vf = *(const short8*)(VtS + ((n * 2 + ks) * 64 + lane) * 8);
                        o_acc[n] = __builtin_amdgcn_mfma_f32_16x16x32_bf16(pfk, vf, o_acc[n], 0, 0, 0);
                    }
                }
            }
        }
        __syncthreads();
    }

    float inv[4];
#pragma unroll
    for (int r = 0; r < 4; ++r) inv[r] = 1.f / l_i[r];
#pragma unroll
    for (int n = 0; n < 8; ++n)
#pragma unroll
        for (int r = 0; r < 4; ++r) {
            const int query = s0 + q4 * 4 + r;
            AO[((size_t)(b * Ss + query)) * Hh + h * HDd + n * 16 + l15] = f2bf(o_acc[n][r] * inv[r]);
        }
}

// ---------------------------------------------------------------- host
extern "C" void kernel_launch(void* const* d_in, const int* in_sizes, int n_in,
                              void* d_out, int out_size, void* d_ws, size_t ws_size,
                              hipStream_t stream) {
    const float* X    = (const float*)d_in[0];
    const float* cosp = (const float*)d_in[1];
    const float* sinp = (const float*)d_in[2];
    const float* Wqkv = (const float*)d_in[3];
    const float* bqkv = (const float*)d_in[4];
    const float* Wout = (const float*)d_in[5];
    const float* bout = (const float*)d_in[6];
    float* out = (float*)d_out;

    char* ws = (char*)d_ws;
    size_t off = 0;
    auto carve = [&](size_t bytes) { void* p = ws + off; off += bytes; return p; };
    unsigned short* Xb    = (unsigned short*)carve((size_t)Mm * Hh * 2);        // 16 MB
    unsigned short* Wqkvb = (unsigned short*)carve((size_t)3 * Hh * Hh * 2);    // 24 MB
    unsigned short* Woutb = (unsigned short*)carve((size_t)Hh * Hh * 2);        //  8 MB
    unsigned short* QKVb  = (unsigned short*)carve((size_t)Mm * 3 * Hh * 2);    // 48 MB
    unsigned short* Qr    = (unsigned short*)carve((size_t)Mm * Hh * 2);        // 16 MB
    unsigned short* Kr    = (unsigned short*)carve((size_t)Mm * Hh * 2);        // 16 MB
    unsigned short* Vt    = (unsigned short*)carve((size_t)Mm * Hh * 2);        // 16 MB
    unsigned short* AOb   = (unsigned short*)carve((size_t)Mm * Hh * 2);        // 16 MB

    cast_f32_to_bf16<<<(Mm * Hh) / 1024, 256, 0, stream>>>(X, Xb, Mm * Hh);
    cast_f32_to_bf16<<<(3 * Hh * Hh) / 1024, 256, 0, stream>>>(Wqkv, Wqkvb, 3 * Hh * Hh);
    cast_f32_to_bf16<<<(Hh * Hh) / 1024, 256, 0, stream>>>(Wout, Woutb, Hh * Hh);

    gemm256<unsigned short><<<dim3((3 * Hh) / 256, Mm / 256), 512, 0, stream>>>(
        Xb, Wqkvb, bqkv, QKVb, Mm, 3 * Hh, Hh);

    rope_repack<<<dim3(Ss, Bb), 256, 0, stream>>>(QKVb, cosp, sinp, Qr, Kr);

    v_transpose<<<dim3(Ss / 64, HDd / 64, Bb * NHh), 256, 0, stream>>>(QKVb, Vt);

    attn_fwd<<<dim3(Ss / 128, Bb * NHh), 512, 0, stream>>>(Qr, Kr, Vt, AOb);

    gemm_bt<float><<<dim3(Hh / 128, Mm / 128), 256, 0, stream>>>(
        AOb, Woutb, bout, out, Mm, Hh, Hh);
}

// Round 8
// 479.845 us; speedup vs baseline: 1.7379x; 1.7379x over previous
//
#include <hip/hip_runtime.h>
#include <hip/hip_bf16.h>
#include <type_traits>

// Problem constants
#define Bb  2
#define Ss  2048
#define Hh  2048
#define NHh 16
#define HDd 128
#define Mm  (Bb * Ss)   // 4096 rows

typedef __attribute__((ext_vector_type(8))) short short8;  // 8 bf16 (4 VGPRs)
typedef __attribute__((ext_vector_type(4))) float f32x4;   // MFMA accumulator

#if __has_builtin(__builtin_amdgcn_exp2f)
#define EXPFN(x) __builtin_amdgcn_exp2f(x)
#define QSCALE 0.12751744416668577f   /* (1/sqrt(128)) * log2(e), folded into Q */
#else
#define EXPFN(x) __expf(x)
#define QSCALE 0.08838834764831845f   /* 1/sqrt(128) folded into Q */
#endif

__device__ __forceinline__ float bf2f(unsigned short u) {
    unsigned int x = ((unsigned int)u) << 16;
    return __builtin_bit_cast(float, x);
}
__device__ __forceinline__ unsigned short f2bf(float f) {
    unsigned int x = __builtin_bit_cast(unsigned int, f);
    x += 0x7fffu + ((x >> 16) & 1u);   // RNE
    return (unsigned short)(x >> 16);
}

// raw workgroup barrier WITHOUT the vmcnt(0)/lgkmcnt(0) drain __syncthreads() emits.
__device__ __forceinline__ void blk_barrier() {
    asm volatile("" ::: "memory");
    __builtin_amdgcn_s_barrier();
    asm volatile("" ::: "memory");
}

// ---------------------------------------------------------------- cast fp32->bf16
__global__ __launch_bounds__(256) void cast_f32_to_bf16(const float* __restrict__ in,
                                                        unsigned short* __restrict__ out, int n) {
    int i = (blockIdx.x * 256 + threadIdx.x) * 4;
    if (i + 3 < n) {
        float4 f = *(const float4*)(in + i);
        ushort4 o;
        o.x = f2bf(f.x); o.y = f2bf(f.y); o.z = f2bf(f.z); o.w = f2bf(f.w);
        *(ushort4*)(out + i) = o;
    }
}

// ---------------------------------------------------------------- GEMM: C = A * Bt^T + bias (128x128, m97)
// Used for the out-projection (N=2048 -> 512 blocks, full chip).
template <typename OutT>
__global__ __launch_bounds__(256) void gemm_bt(const unsigned short* __restrict__ A,
                                               const unsigned short* __restrict__ Bt,
                                               const float* __restrict__ bias,
                                               OutT* __restrict__ C,
                                               int M, int N, int K) {
    __shared__ unsigned short As[128 * 64];
    __shared__ unsigned short Bs[128 * 64];
    const int tid  = threadIdx.x;
    const int lane = tid & 63;
    const int wave = tid >> 6;
    const int q4 = lane >> 4, l15 = lane & 15;
    const int m0 = blockIdx.y * 128, n0 = blockIdx.x * 128;
    const int wm = (wave >> 1) * 64, wn = (wave & 1) * 64;

    f32x4 acc[4][4] = {};

    for (int k0 = 0; k0 < K; k0 += 64) {
#pragma unroll
        for (int t = 0; t < 4; ++t) {
            const int chunk = t * 256 + tid;
            const int row = chunk >> 3, c8 = chunk & 7;
            const unsigned short* ga = A  + (size_t)(m0 + row) * K + (k0 + c8 * 8);
            const unsigned short* gb = Bt + (size_t)(n0 + row) * K + (k0 + c8 * 8);
            __builtin_amdgcn_global_load_lds((const __attribute__((address_space(1))) unsigned int*)ga,
                                             (__attribute__((address_space(3))) unsigned int*)(As + chunk * 8),
                                             16, 0, 0);
            __builtin_amdgcn_global_load_lds((const __attribute__((address_space(1))) unsigned int*)gb,
                                             (__attribute__((address_space(3))) unsigned int*)(Bs + chunk * 8),
                                             16, 0, 0);
        }
        __syncthreads();
#pragma unroll
        for (int kk = 0; kk < 2; ++kk) {
            short8 a[4], b[4];
#pragma unroll
            for (int i = 0; i < 4; ++i)
                a[i] = *(const short8*)(As + (wm + i * 16 + l15) * 64 + kk * 32 + q4 * 8);
#pragma unroll
            for (int j = 0; j < 4; ++j)
                b[j] = *(const short8*)(Bs + (wn + j * 16 + l15) * 64 + kk * 32 + q4 * 8);
#pragma unroll
            for (int i = 0; i < 4; ++i)
#pragma unroll
                for (int j = 0; j < 4; ++j)
                    acc[i][j] = __builtin_amdgcn_mfma_f32_16x16x32_bf16(a[i], b[j], acc[i][j], 0, 0, 0);
        }
        __syncthreads();
    }

#pragma unroll
    for (int i = 0; i < 4; ++i) {
#pragma unroll
        for (int j = 0; j < 4; ++j) {
            const int col = n0 + wn + j * 16 + l15;
            const float bv = bias[col];
            const size_t base = (size_t)(m0 + wm + i * 16 + q4 * 4) * N + col;
#pragma unroll
            for (int r = 0; r < 4; ++r) {
                float v = acc[i][j][r] + bv;
                if constexpr (std::is_same_v<OutT, float>)
                    C[base + (size_t)r * N] = v;
                else
                    C[base + (size_t)r * N] = f2bf(v);
            }
        }
    }
}

// ---------------------------------------------------------------- GEMM 256x256, 8-phase counted-vmcnt
// REVERTED to the R6-verified version (162 us, passed twice). R7's cross-phase register
// double-buffer spilled (VGPR pinned at 128, WRITE_SIZE 49->700 MB scratch). Frozen.
template <typename OutT>
__global__ __launch_bounds__(512, 2) void gemm256(const unsigned short* __restrict__ A,
                                                  const unsigned short* __restrict__ Bt,
                                                  const float* __restrict__ bias,
                                                  OutT* __restrict__ C,
                                                  int M, int N, int K) {
    __shared__ unsigned short LA[2][2][16][512];   // [buf][kk][seg][lane*8]  64 KB
    __shared__ unsigned short LB[2][2][16][512];   // 64 KB
    const int tid = threadIdx.x;
    const int lane = tid & 63, wave = tid >> 6;    // 8 waves
    const int q4 = lane >> 4, l15 = lane & 15;
    const int wr = wave >> 2, wc = wave & 3;       // 2x4 wave grid; per-wave 128x64 out
    const int m0 = blockIdx.y * 256, n0 = blockIdx.x * 256;
    const int NT = K >> 6;                         // K-tiles (K=2048 -> 32)

    f32x4 acc[8][4] = {};

    auto stage = [&](const unsigned short* G, int r0, unsigned short* R, int kofs) {
#pragma unroll
        for (int it = 0; it < 2; ++it) {
            const int s = it * 8 + wave;
            const unsigned short* src = G + (size_t)(r0 + s * 16 + l15) * K + kofs + q4 * 8;
            __builtin_amdgcn_global_load_lds((const __attribute__((address_space(1))) unsigned int*)src,
                                             (__attribute__((address_space(3))) unsigned int*)(R + (s * 64 + lane) * 8),
                                             16, 0, 0);
        }
    };

    stage(A,  m0, &LA[0][0][0][0], 0);     // 1-2   buf0.A.k0  (tile 0)
    stage(Bt, n0, &LB[0][0][0][0], 0);     // 3-4   buf0.B.k0
    stage(A,  m0, &LA[0][1][0][0], 32);    // 5-6   buf0.A.k1
    stage(Bt, n0, &LB[0][1][0][0], 32);    // 7-8   buf0.B.k1
    stage(A,  m0, &LA[1][0][0][0], 64);    // 9-10  buf1.A.k0  (tile 1)
    stage(Bt, n0, &LB[1][0][0][0], 64);    // 11-12 buf1.B.k0
    stage(A,  m0, &LA[1][1][0][0], 96);    // 13-14 buf1.A.k1
    asm volatile("s_waitcnt vmcnt(10)" ::: "memory");   // loads 1-4 landed (tile0 kk0)
    blk_barrier();

#define MFMA16(av, bv, cv) __builtin_amdgcn_mfma_f32_16x16x32_bf16(av, bv, cv, 0, 0, 0)

#define PHASE_A(d, h, STAGE_STMT)                                                 \
    {                                                                             \
        short8 b0 = *(const short8*)&LB[d][h][wc * 4 + 0][lane * 8];              \
        short8 b1 = *(const short8*)&LB[d][h][wc * 4 + 1][lane * 8];              \
        _Pragma("unroll")                                                         \
        for (int m = 0; m < 8; ++m)                                               \
            aa[m] = *(const short8*)&LA[d][h][wr * 8 + m][lane * 8];              \
        STAGE_STMT;                                                               \
        blk_barrier();                                                            \
        __builtin_amdgcn_s_setprio(1);                                            \
        _Pragma("unroll")                                                         \
        for (int m = 0; m < 8; ++m) {                                             \
            acc[m][0] = MFMA16(aa[m], b0, acc[m][0]);                             \
            acc[m][1] = MFMA16(aa[m], b1, acc[m][1]);                             \
        }                                                                         \
        __builtin_amdgcn_s_setprio(0);                                            \
        asm volatile("s_waitcnt lgkmcnt(0)" ::: "memory");                        \
        blk_barrier();                                                            \
    }

#define PHASE_B(d, h, STAGE_STMT)                                                 \
    {                                                                             \
        short8 b2 = *(const short8*)&LB[d][h][wc * 4 + 2][lane * 8];              \
        short8 b3 = *(const short8*)&LB[d][h][wc * 4 + 3][lane * 8];              \
        STAGE_STMT;                                                               \
        asm volatile("s_waitcnt vmcnt(6)" ::: "memory");                          \
        blk_barrier();                                                            \
        __builtin_amdgcn_s_setprio(1);                                            \
        _Pragma("unroll")                                                         \
        for (int m = 0; m < 8; ++m) {                                             \
            acc[m][2] = MFMA16(aa[m], b2, acc[m][2]);                             \
            acc[m][3] = MFMA16(aa[m], b3, acc[m][3]);                             \
        }                                                                         \
        __builtin_amdgcn_s_setprio(0);                                            \
        asm volatile("s_waitcnt lgkmcnt(0)" ::: "memory");                        \
        blk_barrier();                                                            \
    }

#pragma unroll 1
    for (int i = 0; i < NT / 2; ++i) {
        const int t1 = 2 * i + 1, t2 = 2 * i + 2, t3 = 2 * i + 3;
        short8 aa[8];
        // tile 2i from buf0
        PHASE_A(0, 0, { stage(Bt, n0, &LB[1][1][0][0], t1 * 64 + 32); });                 // P1
        PHASE_B(0, 0, { if (t2 < NT) stage(A,  m0, &LA[0][0][0][0], t2 * 64); });         // P2
        PHASE_A(0, 1, { if (t2 < NT) stage(Bt, n0, &LB[0][0][0][0], t2 * 64); });         // P3
        PHASE_B(0, 1, { if (t2 < NT) stage(A,  m0, &LA[0][1][0][0], t2 * 64 + 32); });    // P4
        // tile 2i+1 from buf1
        PHASE_A(1, 0, { if (t2 < NT) stage(Bt, n0, &LB[0][1][0][0], t2 * 64 + 32); });    // P5
        PHASE_B(1, 0, { if (t3 < NT) stage(A,  m0, &LA[1][0][0][0], t3 * 64); });         // P6
        PHASE_A(1, 1, { if (t3 < NT) stage(Bt, n0, &LB[1][0][0][0], t3 * 64); });         // P7
        PHASE_B(1, 1, { if (t3 < NT) stage(A,  m0, &LA[1][1][0][0], t3 * 64 + 32); });    // P8
    }
#undef PHASE_A
#undef PHASE_B
#undef MFMA16

    // C/D layout: col = lane&15, row = (lane>>4)*4 + r   [m89/m91 verified]
#pragma unroll
    for (int m = 0; m < 8; ++m) {
#pragma unroll
        for (int n = 0; n < 4; ++n) {
            const int col = n0 + wc * 64 + n * 16 + l15;
            const float bv = bias[col];
            const size_t base = (size_t)(m0 + wr * 128 + m * 16 + q4 * 4) * N + col;
#pragma unroll
            for (int r = 0; r < 4; ++r) {
                float v = acc[m][n][r] + bv;
                if constexpr (std::is_same_v<OutT, float>)
                    C[base + (size_t)r * N] = v;
                else
                    C[base + (size_t)r * N] = f2bf(v);
            }
        }
    }
}

// ---------------------------------------------------------------- RoPE + repack Q,K to [B*NH][S][HD]
__global__ __launch_bounds__(256) void rope_repack(const unsigned short* __restrict__ qkv, // [B][S][3H] bf16
                                                   const float* __restrict__ cosp,         // [S][HD]
                                                   const float* __restrict__ sinp,
                                                   unsigned short* __restrict__ Qr,
                                                   unsigned short* __restrict__ Kr) {
    const int s = blockIdx.x, b = blockIdx.y, tid = threadIdx.x;
    const unsigned short* base = qkv + (size_t)(b * Ss + s) * (3 * Hh);
#pragma unroll
    for (int t = 0; t < 4; ++t) {
        const int p = t * 256 + tid;     // 0..1023 : 16 heads x 64 pairs
        const int h = p >> 6, d = p & 63;
        const float c  = cosp[s * HDd + d];
        const float sn = sinp[s * HDd + d];
        const size_t o = ((size_t)(b * NHh + h) * Ss + s) * HDd;
        float q1 = bf2f(base[h * HDd + d]), q2 = bf2f(base[h * HDd + d + 64]);
        Qr[o + d]      = f2bf((q1 * c - q2 * sn) * QSCALE);
        Qr[o + d + 64] = f2bf((q2 * c + q1 * sn) * QSCALE);
        float k1 = bf2f(base[Hh + h * HDd + d]), k2 = bf2f(base[Hh + h * HDd + d + 64]);
        Kr[o + d]      = f2bf(k1 * c - k2 * sn);
        Kr[o + d + 64] = f2bf(k2 * c + k1 * sn);
    }
}

// ---------------------------------------------------------------- V transpose: qkv V-part -> Vt [B*NH][HD][S]
__global__ __launch_bounds__(256) void v_transpose(const unsigned short* __restrict__ qkv,
                                                   unsigned short* __restrict__ Vt) {
    __shared__ unsigned short T[64 * 64];
    const int tid = threadIdx.x;
    const int st = blockIdx.x;
    const int dt = blockIdx.y;
    const int bh = blockIdx.z;
    const int b = bh >> 4, h = bh & 15;
#pragma unroll
    for (int it = 0; it < 2; ++it) {
        const int chunk = it * 256 + tid;
        const int row = chunk >> 3, c8 = chunk & 7;
        const unsigned short* src = qkv + ((size_t)(b * Ss + st * 64 + row)) * (3 * Hh)
                                        + 2 * Hh + h * HDd + dt * 64 + c8 * 8;
        uint4 v = *(const uint4*)src;
        *(uint4*)(T + row * 64 + ((c8 ^ (row & 7)) * 8)) = v;
    }
    __syncthreads();
#pragma unroll
    for (int it = 0; it < 2; ++it) {
        const int chunk = it * 256 + tid;
        const int drow = chunk & 63;
        const int c8s = chunk >> 6;
        ushort4 lo, hi;
        unsigned short tmp[8];
#pragma unroll
        for (int j = 0; j < 8; ++j) {
            const int sl = c8s * 8 + j;
            tmp[j] = T[sl * 64 + (((drow >> 3) ^ (sl & 7)) * 8) + (drow & 7)];
        }
        lo.x = tmp[0]; lo.y = tmp[1]; lo.z = tmp[2]; lo.w = tmp[3];
        hi.x = tmp[4]; hi.y = tmp[5]; hi.z = tmp[6]; hi.w = tmp[7];
        unsigned short* dst = Vt + ((size_t)bh * HDd + dt * 64 + drow) * Ss + st * 64 + c8s * 8;
        *(ushort4*)(dst)     = lo;
        *(ushort4*)(dst + 4) = hi;
    }
}

// ---------------------------------------------------------------- flash attention (causal, FA2-paired)
// 8 waves/block (512 thr): waves 0-3 own qA=blockIdx.x strips, waves 4-7 own qB=31-qA.
// R8: async staging (T14/T3). OLD: gload_lds K,V -> __syncthreads (vmcnt(0) FULL DRAIN:
// HBM latency on the critical path every tile, 2 blocks/CU can't hide it). NEW:
//  - K double-buffered in LDS: K(t+1) issued at top of iter t, published by vmcnt(0)+
//    barrier at END of t (a whole iteration of slack -> wait ~free).
//  - V reg-staged: V(t) -> 2x uint4 regs (issued BEFORE K so compiler's ds_write wait is
//    vmcnt(2), K stays in flight; asm "" memory fence pins issue order), ds_written after
//    softmax, published by lgkmcnt(0)+barrier. HBM latency hides under QK^T/softmax.
// Race ledger: VtS last read by PV(t-1) (MFMA operand dep) before end-of-(t-1) barrier;
// ds_write V(t) after it. Ks[cur^1] last read at t-1 (QK^T consumed before mid-barrier),
// rewritten by gloads issued after end-of-(t-1) barrier. K(t+1) published before t+1's
// QK^T by end-of-t vmcnt(0)+barrier. Barriers unconditional; kv_end/cur block-uniform.
__global__ __launch_bounds__(512, 4) void attn_fwd(const unsigned short* __restrict__ Qr,
                                                   const unsigned short* __restrict__ Kr,
                                                   const unsigned short* __restrict__ Vt,
                                                   unsigned short* __restrict__ AO) {  // [B][S][H] bf16
    __shared__ unsigned short Ks[2][16 * 64 * 8]; // K dbuf: 2 x 16 segs (g,kc) x 64 x 8   (32 KB)
    __shared__ unsigned short VtS[16 * 64 * 8];   // 16 segs (n,ks) x 64 lanes x 8 bf16    (16 KB)
    __shared__ unsigned short Ps[8][16 * 72];     // per-wave P round-trip                 (18.4 KB)
    const int tid = threadIdx.x;
    const int lane = tid & 63, wave = tid >> 6;
    const int q4 = lane >> 4, l15 = lane & 15;
    const int qA = (int)blockIdx.x;
    const int qB = 31 - qA;
    const int bh = blockIdx.y;
    const int b = bh >> 4, h = bh & 15;
    const unsigned short* Qh  = Qr + (size_t)bh * Ss * HDd;
    const unsigned short* Kh  = Kr + (size_t)bh * Ss * HDd;
    const unsigned short* Vth = Vt + (size_t)bh * HDd * Ss;

    const int mt = wave >> 2;
    const int wg = wave & 3;
    const int s0 = (mt ? qB : qA) * 64 + wg * 16;

    short8 qf[4];
#pragma unroll
    for (int kc = 0; kc < 4; ++kc)
        qf[kc] = *(const short8*)(Qh + (size_t)(s0 + l15) * HDd + kc * 32 + q4 * 8);

    f32x4 o_acc[8] = {};
    float m_i[4], l_i[4];
#pragma unroll
    for (int r = 0; r < 4; ++r) { m_i[r] = -1e30f; l_i[r] = 0.f; }

    // stage K tile (64 keys) fragment-major into Ks[buf]
    auto stageK = [&](int t0k, int buf) {
#pragma unroll
        for (int it = 0; it < 2; ++it) {
            const int s = it * 8 + wave;
            const int g = s >> 2, kc = s & 3;
            const unsigned short* gk = Kh + (size_t)(t0k + g * 16 + l15) * HDd + kc * 32 + q4 * 8;
            __builtin_amdgcn_global_load_lds((const __attribute__((address_space(1))) unsigned int*)gk,
                                             (__attribute__((address_space(3))) unsigned int*)(Ks[buf] + (s * 64 + lane) * 8),
                                             16, 0, 0);
        }
    };

    const int kv_end = qB * 64 + 64;   // qB > qA always; covers both tiles' needs

    // prologue: K(0) resident + published
    stageK(0, 0);
    asm volatile("s_waitcnt vmcnt(0)" ::: "memory");
    blk_barrier();

    int cur = 0;
    for (int t0 = 0; t0 < kv_end; t0 += 64) {
        // issue V(t0) -> regs FIRST (oldest VMEM: compiler's ds_write wait = vmcnt(2))
        uint4 vreg[2];
#pragma unroll
        for (int it = 0; it < 2; ++it) {
            const int s = it * 8 + wave;
            const int n = s >> 1, ks = s & 1;
            vreg[it] = *(const uint4*)(Vth + (size_t)(n * 16 + l15) * Ss + t0 + ks * 32 + q4 * 8);
        }
        asm volatile("" ::: "memory");   // pin order: V loads before K gloads
        // issue K(t0+64) -> Ks[cur^1] (flies across the whole iteration)
        if (t0 + 64 < kv_end) stageK(t0 + 64, cur ^ 1);

        const unsigned short* Kc = Ks[cur];
        if (t0 <= s0 + 15) {   // wave-uniform: tile has >=1 unmasked key for these rows
            float sv[4][4];
#pragma unroll
            for (int g = 0; g < 4; ++g)
#pragma unroll
                for (int r = 0; r < 4; ++r) sv[g][r] = -1e30f;
#pragma unroll
            for (int g = 0; g < 4; ++g) {
                if (t0 + g * 16 <= s0 + 15) {
                    f32x4 scg = {};
#pragma unroll
                    for (int kc = 0; kc < 4; ++kc) {
                        short8 kf = *(const short8*)(Kc + ((g * 4 + kc) * 64 + lane) * 8);
                        scg = __builtin_amdgcn_mfma_f32_16x16x32_bf16(qf[kc], kf, scg, 0, 0, 0);
                    }
                    const int key = t0 + g * 16 + l15;
#pragma unroll
                    for (int r = 0; r < 4; ++r)
                        sv[g][r] = (key <= s0 + q4 * 4 + r) ? scg[r] : -1e30f;
                }
            }
            float mnew[4], alpha[4], sm[4];
            bool need = false;
#pragma unroll
            for (int r = 0; r < 4; ++r) {
                float mx = fmaxf(fmaxf(sv[0][r], sv[1][r]), fmaxf(sv[2][r], sv[3][r]));
#pragma unroll
                for (int off = 1; off < 16; off <<= 1)
                    mx = fmaxf(mx, __shfl_xor(mx, off, 16));
                mnew[r]  = fmaxf(m_i[r], mx);
                need = need || (mnew[r] > m_i[r]);
                alpha[r] = EXPFN(m_i[r] - mnew[r]);
                m_i[r] = mnew[r];
            }
            float p[4][4];
#pragma unroll
            for (int g = 0; g < 4; ++g)
#pragma unroll
                for (int r = 0; r < 4; ++r)
                    p[g][r] = EXPFN(sv[g][r] - mnew[r]);
#pragma unroll
            for (int r = 0; r < 4; ++r) {
                float s2 = (p[0][r] + p[1][r]) + (p[2][r] + p[3][r]);
#pragma unroll
                for (int off = 1; off < 16; off <<= 1)
                    s2 += __shfl_xor(s2, off, 16);
                sm[r] = s2;
            }
            if (__any(need)) {
#pragma unroll
                for (int r = 0; r < 4; ++r) l_i[r] *= alpha[r];
#pragma unroll
                for (int n = 0; n < 8; ++n)
#pragma unroll
                    for (int r = 0; r < 4; ++r)
                        o_acc[n][r] *= alpha[r];
            }
#pragma unroll
            for (int r = 0; r < 4; ++r) l_i[r] += sm[r];

            // P: C-layout -> per-wave LDS -> A-layout (within-wave)
            unsigned short* Pw = &Ps[wave][0];
#pragma unroll
            for (int g = 0; g < 4; ++g)
#pragma unroll
                for (int r = 0; r < 4; ++r)
                    Pw[(q4 * 4 + r) * 72 + g * 16 + l15] = f2bf(p[g][r]);
        }

        // publish V(t0): ds_write from regs (compiler waits vmcnt(2): V done, K flying)
#pragma unroll
        for (int it = 0; it < 2; ++it) {
            const int s = it * 8 + wave;
            *(uint4*)(VtS + (s * 64 + lane) * 8) = vreg[it];
        }
        asm volatile("s_waitcnt lgkmcnt(0)" ::: "memory");
        blk_barrier();

        if (t0 <= s0 + 15) {
            const unsigned short* Pw = &Ps[wave][0];
#pragma unroll
            for (int ks = 0; ks < 2; ++ks) {
                if (t0 + ks * 32 <= s0 + 15) {
                    short8 pfk = *(const short8*)(Pw + l15 * 72 + ks * 32 + q4 * 8);
#pragma unroll
                    for (int n = 0; n < 8; ++n) {
                        short8 vf = *(const short8*)(VtS + ((n * 2 + ks) * 64 + lane) * 8);
                        o_acc[n] = __builtin_amdgcn_mfma_f32_16x16x32_bf16(pfk, vf, o_acc[n], 0, 0, 0);
                    }
                }
            }
        }

        // publish K(t0+64) (issued a full iteration ago -> near-free wait); free VtS
        asm volatile("s_waitcnt vmcnt(0)" ::: "memory");
        blk_barrier();
        cur ^= 1;
    }

    float inv[4];
#pragma unroll
    for (int r = 0; r < 4; ++r) inv[r] = 1.f / l_i[r];
#pragma unroll
    for (int n = 0; n < 8; ++n)
#pragma unroll
        for (int r = 0; r < 4; ++r) {
            const int query = s0 + q4 * 4 + r;
            AO[((size_t)(b * Ss + query)) * Hh + h * HDd + n * 16 + l15] = f2bf(o_acc[n][r] * inv[r]);
        }
}

// ---------------------------------------------------------------- host
extern "C" void kernel_launch(void* const* d_in, const int* in_sizes, int n_in,
                              void* d_out, int out_size, void* d_ws, size_t ws_size,
                              hipStream_t stream) {
    const float* X    = (const float*)d_in[0];
    const float* cosp = (const float*)d_in[1];
    const float* sinp = (const float*)d_in[2];
    const float* Wqkv = (const float*)d_in[3];
    const float* bqkv = (const float*)d_in[4];
    const float* Wout = (const float*)d_in[5];
    const float* bout = (const float*)d_in[6];
    float* out = (float*)d_out;

    char* ws = (char*)d_ws;
    size_t off = 0;
    auto carve = [&](size_t bytes) { void* p = ws + off; off += bytes; return p; };
    unsigned short* Xb    = (unsigned short*)carve((size_t)Mm * Hh * 2);        // 16 MB
    unsigned short* Wqkvb = (unsigned short*)carve((size_t)3 * Hh * Hh * 2);    // 24 MB
    unsigned short* Woutb = (unsigned short*)carve((size_t)Hh * Hh * 2);        //  8 MB
    unsigned short* QKVb  = (unsigned short*)carve((size_t)Mm * 3 * Hh * 2);    // 48 MB
    unsigned short* Qr    = (unsigned short*)carve((size_t)Mm * Hh * 2);        // 16 MB
    unsigned short* Kr    = (unsigned short*)carve((size_t)Mm * Hh * 2);        // 16 MB
    unsigned short* Vt    = (unsigned short*)carve((size_t)Mm * Hh * 2);        // 16 MB
    unsigned short* AOb   = (unsigned short*)carve((size_t)Mm * Hh * 2);        // 16 MB

    cast_f32_to_bf16<<<(Mm * Hh) / 1024, 256, 0, stream>>>(X, Xb, Mm * Hh);
    cast_f32_to_bf16<<<(3 * Hh * Hh) / 1024, 256, 0, stream>>>(Wqkv, Wqkvb, 3 * Hh * Hh);
    cast_f32_to_bf16<<<(Hh * Hh) / 1024, 256, 0, stream>>>(Wout, Woutb, Hh * Hh);

    gemm256<unsigned short><<<dim3((3 * Hh) / 256, Mm / 256), 512, 0, stream>>>(
        Xb, Wqkvb, bqkv, QKVb, Mm, 3 * Hh, Hh);

    rope_repack<<<dim3(Ss, Bb), 256, 0, stream>>>(QKVb, cosp, sinp, Qr, Kr);

    v_transpose<<<dim3(Ss / 64, HDd / 64, Bb * NHh), 256, 0, stream>>>(QKVb, Vt);

    attn_fwd<<<dim3(Ss / 128, Bb * NHh), 512, 0, stream>>>(Qr, Kr, Vt, AOb);

    gemm_bt<float><<<dim3(Hh / 128, Mm / 128), 256, 0, stream>>>(
        AOb, Woutb, bout, out, Mm, Hh, Hh);
}

// Round 9
// 460.399 us; speedup vs baseline: 1.8113x; 1.0422x over previous
//
#include <hip/hip_runtime.h>
#include <hip/hip_bf16.h>
#include <type_traits>

// Problem constants
#define Bb  2
#define Ss  2048
#define Hh  2048
#define NHh 16
#define HDd 128
#define Mm  (Bb * Ss)   // 4096 rows

typedef __attribute__((ext_vector_type(8))) short short8;  // 8 bf16 (4 VGPRs)
typedef __attribute__((ext_vector_type(4))) float f32x4;   // MFMA accumulator

#if __has_builtin(__builtin_amdgcn_exp2f)
#define EXPFN(x) __builtin_amdgcn_exp2f(x)
#define QSCALE 0.12751744416668577f   /* (1/sqrt(128)) * log2(e), folded into Q */
#else
#define EXPFN(x) __expf(x)
#define QSCALE 0.08838834764831845f   /* 1/sqrt(128) folded into Q */
#endif

__device__ __forceinline__ float bf2f(unsigned short u) {
    unsigned int x = ((unsigned int)u) << 16;
    return __builtin_bit_cast(float, x);
}
__device__ __forceinline__ unsigned short f2bf(float f) {
    unsigned int x = __builtin_bit_cast(unsigned int, f);
    x += 0x7fffu + ((x >> 16) & 1u);   // RNE
    return (unsigned short)(x >> 16);
}

// raw workgroup barrier WITHOUT the vmcnt(0)/lgkmcnt(0) drain __syncthreads() emits.
__device__ __forceinline__ void blk_barrier() {
    asm volatile("" ::: "memory");
    __builtin_amdgcn_s_barrier();
    asm volatile("" ::: "memory");
}

// ---------------------------------------------------------------- fused cast fp32->bf16 (3 buffers, 1 launch)
// Segment sizes in blocks: X=8192, Wqkv=12288, Wout=4096 (each block: 256 thr x 1 float4).
__global__ __launch_bounds__(256) void cast3(const float* __restrict__ a, unsigned short* __restrict__ ao,
                                             const float* __restrict__ b, unsigned short* __restrict__ bo,
                                             const float* __restrict__ c, unsigned short* __restrict__ co) {
    const int bid = blockIdx.x;
    const float* in; unsigned short* out; int base;
    if (bid < 8192)        { in = a; out = ao; base = bid; }
    else if (bid < 20480)  { in = b; out = bo; base = bid - 8192; }
    else                   { in = c; out = co; base = bid - 20480; }
    const int i = (base * 256 + threadIdx.x) * 4;
    float4 f = *(const float4*)(in + i);
    ushort4 o;
    o.x = f2bf(f.x); o.y = f2bf(f.y); o.z = f2bf(f.z); o.w = f2bf(f.w);
    *(ushort4*)(out + i) = o;
}

// ---------------------------------------------------------------- GEMM: C = A * Bt^T + bias (128x128, m97)
// Used for the out-projection (N=2048 -> 512 blocks, full chip).
template <typename OutT>
__global__ __launch_bounds__(256) void gemm_bt(const unsigned short* __restrict__ A,
                                               const unsigned short* __restrict__ Bt,
                                               const float* __restrict__ bias,
                                               OutT* __restrict__ C,
                                               int M, int N, int K) {
    __shared__ unsigned short As[128 * 64];
    __shared__ unsigned short Bs[128 * 64];
    const int tid  = threadIdx.x;
    const int lane = tid & 63;
    const int wave = tid >> 6;
    const int q4 = lane >> 4, l15 = lane & 15;
    const int m0 = blockIdx.y * 128, n0 = blockIdx.x * 128;
    const int wm = (wave >> 1) * 64, wn = (wave & 1) * 64;

    f32x4 acc[4][4] = {};

    for (int k0 = 0; k0 < K; k0 += 64) {
#pragma unroll
        for (int t = 0; t < 4; ++t) {
            const int chunk = t * 256 + tid;
            const int row = chunk >> 3, c8 = chunk & 7;
            const unsigned short* ga = A  + (size_t)(m0 + row) * K + (k0 + c8 * 8);
            const unsigned short* gb = Bt + (size_t)(n0 + row) * K + (k0 + c8 * 8);
            __builtin_amdgcn_global_load_lds((const __attribute__((address_space(1))) unsigned int*)ga,
                                             (__attribute__((address_space(3))) unsigned int*)(As + chunk * 8),
                                             16, 0, 0);
            __builtin_amdgcn_global_load_lds((const __attribute__((address_space(1))) unsigned int*)gb,
                                             (__attribute__((address_space(3))) unsigned int*)(Bs + chunk * 8),
                                             16, 0, 0);
        }
        __syncthreads();
#pragma unroll
        for (int kk = 0; kk < 2; ++kk) {
            short8 a[4], b[4];
#pragma unroll
            for (int i = 0; i < 4; ++i)
                a[i] = *(const short8*)(As + (wm + i * 16 + l15) * 64 + kk * 32 + q4 * 8);
#pragma unroll
            for (int j = 0; j < 4; ++j)
                b[j] = *(const short8*)(Bs + (wn + j * 16 + l15) * 64 + kk * 32 + q4 * 8);
#pragma unroll
            for (int i = 0; i < 4; ++i)
#pragma unroll
                for (int j = 0; j < 4; ++j)
                    acc[i][j] = __builtin_amdgcn_mfma_f32_16x16x32_bf16(a[i], b[j], acc[i][j], 0, 0, 0);
        }
        __syncthreads();
    }

#pragma unroll
    for (int i = 0; i < 4; ++i) {
#pragma unroll
        for (int j = 0; j < 4; ++j) {
            const int col = n0 + wn + j * 16 + l15;
            const float bv = bias[col];
            const size_t base = (size_t)(m0 + wm + i * 16 + q4 * 4) * N + col;
#pragma unroll
            for (int r = 0; r < 4; ++r) {
                float v = acc[i][j][r] + bv;
                if constexpr (std::is_same_v<OutT, float>)
                    C[base + (size_t)r * N] = v;
                else
                    C[base + (size_t)r * N] = f2bf(v);
            }
        }
    }
}

// ---------------------------------------------------------------- GEMM 256x256, 8-phase counted-vmcnt
// R6-verified version (162 us). Frozen: 3 schedule variants all land at ~26% MfmaUtil;
// corrected for 384-block/1.5-round packing (x0.75) the intrinsic is ~850 TF = this
// structure's ceiling at K=2048. No further schedule surgery.
template <typename OutT>
__global__ __launch_bounds__(512, 2) void gemm256(const unsigned short* __restrict__ A,
                                                  const unsigned short* __restrict__ Bt,
                                                  const float* __restrict__ bias,
                                                  OutT* __restrict__ C,
                                                  int M, int N, int K) {
    __shared__ unsigned short LA[2][2][16][512];   // [buf][kk][seg][lane*8]  64 KB
    __shared__ unsigned short LB[2][2][16][512];   // 64 KB
    const int tid = threadIdx.x;
    const int lane = tid & 63, wave = tid >> 6;    // 8 waves
    const int q4 = lane >> 4, l15 = lane & 15;
    const int wr = wave >> 2, wc = wave & 3;       // 2x4 wave grid; per-wave 128x64 out
    const int m0 = blockIdx.y * 256, n0 = blockIdx.x * 256;
    const int NT = K >> 6;                         // K-tiles (K=2048 -> 32)

    f32x4 acc[8][4] = {};

    auto stage = [&](const unsigned short* G, int r0, unsigned short* R, int kofs) {
#pragma unroll
        for (int it = 0; it < 2; ++it) {
            const int s = it * 8 + wave;
            const unsigned short* src = G + (size_t)(r0 + s * 16 + l15) * K + kofs + q4 * 8;
            __builtin_amdgcn_global_load_lds((const __attribute__((address_space(1))) unsigned int*)src,
                                             (__attribute__((address_space(3))) unsigned int*)(R + (s * 64 + lane) * 8),
                                             16, 0, 0);
        }
    };

    stage(A,  m0, &LA[0][0][0][0], 0);     // 1-2   buf0.A.k0  (tile 0)
    stage(Bt, n0, &LB[0][0][0][0], 0);     // 3-4   buf0.B.k0
    stage(A,  m0, &LA[0][1][0][0], 32);    // 5-6   buf0.A.k1
    stage(Bt, n0, &LB[0][1][0][0], 32);    // 7-8   buf0.B.k1
    stage(A,  m0, &LA[1][0][0][0], 64);    // 9-10  buf1.A.k0  (tile 1)
    stage(Bt, n0, &LB[1][0][0][0], 64);    // 11-12 buf1.B.k0
    stage(A,  m0, &LA[1][1][0][0], 96);    // 13-14 buf1.A.k1
    asm volatile("s_waitcnt vmcnt(10)" ::: "memory");   // loads 1-4 landed (tile0 kk0)
    blk_barrier();

#define MFMA16(av, bv, cv) __builtin_amdgcn_mfma_f32_16x16x32_bf16(av, bv, cv, 0, 0, 0)

#define PHASE_A(d, h, STAGE_STMT)                                                 \
    {                                                                             \
        short8 b0 = *(const short8*)&LB[d][h][wc * 4 + 0][lane * 8];              \
        short8 b1 = *(const short8*)&LB[d][h][wc * 4 + 1][lane * 8];              \
        _Pragma("unroll")                                                         \
        for (int m = 0; m < 8; ++m)                                               \
            aa[m] = *(const short8*)&LA[d][h][wr * 8 + m][lane * 8];              \
        STAGE_STMT;                                                               \
        blk_barrier();                                                            \
        __builtin_amdgcn_s_setprio(1);                                            \
        _Pragma("unroll")                                                         \
        for (int m = 0; m < 8; ++m) {                                              \
            acc[m][0] = MFMA16(aa[m], b0, acc[m][0]);                             \
            acc[m][1] = MFMA16(aa[m], b1, acc[m][1]);                             \
        }                                                                         \
        __builtin_amdgcn_s_setprio(0);                                            \
        asm volatile("s_waitcnt lgkmcnt(0)" ::: "memory");                        \
        blk_barrier();                                                            \
    }

#define PHASE_B(d, h, STAGE_STMT)                                                 \
    {                                                                             \
        short8 b2 = *(const short8*)&LB[d][h][wc * 4 + 2][lane * 8];              \
        short8 b3 = *(const short8*)&LB[d][h][wc * 4 + 3][lane * 8];              \
        STAGE_STMT;                                                               \
        asm volatile("s_waitcnt vmcnt(6)" ::: "memory");                          \
        blk_barrier();                                                            \
        __builtin_amdgcn_s_setprio(1);                                            \
        _Pragma("unroll")                                                         \
        for (int m = 0; m < 8; ++m) {                                              \
            acc[m][2] = MFMA16(aa[m], b2, acc[m][2]);                             \
            acc[m][3] = MFMA16(aa[m], b3, acc[m][3]);                             \
        }                                                                         \
        __builtin_amdgcn_s_setprio(0);                                            \
        asm volatile("s_waitcnt lgkmcnt(0)" ::: "memory");                        \
        blk_barrier();                                                            \
    }

#pragma unroll 1
    for (int i = 0; i < NT / 2; ++i) {
        const int t1 = 2 * i + 1, t2 = 2 * i + 2, t3 = 2 * i + 3;
        short8 aa[8];
        // tile 2i from buf0
        PHASE_A(0, 0, { stage(Bt, n0, &LB[1][1][0][0], t1 * 64 + 32); });                 // P1
        PHASE_B(0, 0, { if (t2 < NT) stage(A,  m0, &LA[0][0][0][0], t2 * 64); });         // P2
        PHASE_A(0, 1, { if (t2 < NT) stage(Bt, n0, &LB[0][0][0][0], t2 * 64); });         // P3
        PHASE_B(0, 1, { if (t2 < NT) stage(A,  m0, &LA[0][1][0][0], t2 * 64 + 32); });    // P4
        // tile 2i+1 from buf1
        PHASE_A(1, 0, { if (t2 < NT) stage(Bt, n0, &LB[0][1][0][0], t2 * 64 + 32); });    // P5
        PHASE_B(1, 0, { if (t3 < NT) stage(A,  m0, &LA[1][0][0][0], t3 * 64); });         // P6
        PHASE_A(1, 1, { if (t3 < NT) stage(Bt, n0, &LB[1][0][0][0], t3 * 64); });         // P7
        PHASE_B(1, 1, { if (t3 < NT) stage(A,  m0, &LA[1][1][0][0], t3 * 64 + 32); });    // P8
    }
#undef PHASE_A
#undef PHASE_B
#undef MFMA16

    // C/D layout: col = lane&15, row = (lane>>4)*4 + r   [m89/m91 verified]
#pragma unroll
    for (int m = 0; m < 8; ++m) {
#pragma unroll
        for (int n = 0; n < 4; ++n) {
            const int col = n0 + wc * 64 + n * 16 + l15;
            const float bv = bias[col];
            const size_t base = (size_t)(m0 + wr * 128 + m * 16 + q4 * 4) * N + col;
#pragma unroll
            for (int r = 0; r < 4; ++r) {
                float v = acc[m][n][r] + bv;
                if constexpr (std::is_same_v<OutT, float>)
                    C[base + (size_t)r * N] = v;
                else
                    C[base + (size_t)r * N] = f2bf(v);
            }
        }
    }
}

// ---------------------------------------------------------------- fused RoPE-repack + V-transpose (1 launch)
// blocks [0,4096): rope for (s = bx&2047, b = bx>>11); blocks [4096,6144): v_transpose.
__global__ __launch_bounds__(256) void rope_v(const unsigned short* __restrict__ qkv, // [B][S][3H] bf16
                                              const float* __restrict__ cosp,         // [S][HD]
                                              const float* __restrict__ sinp,
                                              unsigned short* __restrict__ Qr,
                                              unsigned short* __restrict__ Kr,
                                              unsigned short* __restrict__ Vt) {
    __shared__ unsigned short T[64 * 64];
    const int bx = blockIdx.x, tid = threadIdx.x;
    if (bx < 4096) {
        // ---- RoPE + repack Q,K to [B*NH][S][HD] (Q pre-scaled by QSCALE)
        const int s = bx & 2047, b = bx >> 11;
        const unsigned short* base = qkv + (size_t)(b * Ss + s) * (3 * Hh);
#pragma unroll
        for (int t = 0; t < 4; ++t) {
            const int p = t * 256 + tid;     // 0..1023 : 16 heads x 64 pairs
            const int h = p >> 6, d = p & 63;
            const float c  = cosp[s * HDd + d];
            const float sn = sinp[s * HDd + d];
            const size_t o = ((size_t)(b * NHh + h) * Ss + s) * HDd;
            float q1 = bf2f(base[h * HDd + d]), q2 = bf2f(base[h * HDd + d + 64]);
            Qr[o + d]      = f2bf((q1 * c - q2 * sn) * QSCALE);
            Qr[o + d + 64] = f2bf((q2 * c + q1 * sn) * QSCALE);
            float k1 = bf2f(base[Hh + h * HDd + d]), k2 = bf2f(base[Hh + h * HDd + d + 64]);
            Kr[o + d]      = f2bf(k1 * c - k2 * sn);
            Kr[o + d + 64] = f2bf(k2 * c + k1 * sn);
        }
    } else {
        // ---- V transpose: qkv V-part -> Vt [B*NH][HD][S], 64x64 XOR-swizzled tile
        const int t = bx - 4096;              // 0..2047
        const int st = t & 31;                // s-tile
        const int dt = (t >> 5) & 1;          // d-tile
        const int bh = t >> 6;                // 0..31
        const int b = bh >> 4, h = bh & 15;
#pragma unroll
        for (int it = 0; it < 2; ++it) {
            const int chunk = it * 256 + tid;
            const int row = chunk >> 3, c8 = chunk & 7;
            const unsigned short* src = qkv + ((size_t)(b * Ss + st * 64 + row)) * (3 * Hh)
                                            + 2 * Hh + h * HDd + dt * 64 + c8 * 8;
            uint4 v = *(const uint4*)src;
            *(uint4*)(T + row * 64 + ((c8 ^ (row & 7)) * 8)) = v;
        }
        __syncthreads();
#pragma unroll
        for (int it = 0; it < 2; ++it) {
            const int chunk = it * 256 + tid;
            const int drow = chunk & 63;
            const int c8s = chunk >> 6;
            ushort4 lo, hi;
            unsigned short tmp[8];
#pragma unroll
            for (int j = 0; j < 8; ++j) {
                const int sl = c8s * 8 + j;
                tmp[j] = T[sl * 64 + (((drow >> 3) ^ (sl & 7)) * 8) + (drow & 7)];
            }
            lo.x = tmp[0]; lo.y = tmp[1]; lo.z = tmp[2]; lo.w = tmp[3];
            hi.x = tmp[4]; hi.y = tmp[5]; hi.z = tmp[6]; hi.w = tmp[7];
            unsigned short* dst = Vt + ((size_t)bh * HDd + dt * 64 + drow) * Ss + st * 64 + c8s * 8;
            *(ushort4*)(dst)     = lo;
            *(ushort4*)(dst + 4) = hi;
        }
    }
}

// ---------------------------------------------------------------- flash attention (causal, FA2-paired)
// R6-verified version (best measured config: total 471.4). R8's async-staging variant
// regressed ~8 us (extra barrier > drain saved at 2 blocks/CU) -> reverted.
// 8 waves/block (512 thr): waves 0-3 own qA=blockIdx.x strips, waves 4-7 own qB=31-qA.
__global__ __launch_bounds__(512, 4) void attn_fwd(const unsigned short* __restrict__ Qr,
                                                   const unsigned short* __restrict__ Kr,
                                                   const unsigned short* __restrict__ Vt,
                                                   unsigned short* __restrict__ AO) {  // [B][S][H] bf16
    __shared__ unsigned short Ks[16 * 64 * 8];
    __shared__ unsigned short VtS[16 * 64 * 8];
    __shared__ unsigned short Ps[8][16 * 72];
    const int tid = threadIdx.x;
    const int lane = tid & 63, wave = tid >> 6;
    const int q4 = lane >> 4, l15 = lane & 15;
    const int qA = (int)blockIdx.x;
    const int qB = 31 - qA;
    const int bh = blockIdx.y;
    const int b = bh >> 4, h = bh & 15;
    const unsigned short* Qh  = Qr + (size_t)bh * Ss * HDd;
    const unsigned short* Kh  = Kr + (size_t)bh * Ss * HDd;
    const unsigned short* Vth = Vt + (size_t)bh * HDd * Ss;

    const int mt = wave >> 2;
    const int wg = wave & 3;
    const int s0 = (mt ? qB : qA) * 64 + wg * 16;

    short8 qf[4];
#pragma unroll
    for (int kc = 0; kc < 4; ++kc)
        qf[kc] = *(const short8*)(Qh + (size_t)(s0 + l15) * HDd + kc * 32 + q4 * 8);

    f32x4 o_acc[8] = {};
    float m_i[4], l_i[4];
#pragma unroll
    for (int r = 0; r < 4; ++r) { m_i[r] = -1e30f; l_i[r] = 0.f; }

    const int kv_end = qB * 64 + 64;
    for (int t0 = 0; t0 < kv_end; t0 += 64) {
#pragma unroll
        for (int it = 0; it < 2; ++it) {
            const int s = it * 8 + wave;
            const int g = s >> 2, kc = s & 3;
            const unsigned short* gk = Kh + (size_t)(t0 + g * 16 + l15) * HDd + kc * 32 + q4 * 8;
            __builtin_amdgcn_global_load_lds((const __attribute__((address_space(1))) unsigned int*)gk,
                                             (__attribute__((address_space(3))) unsigned int*)(Ks + (s * 64 + lane) * 8),
                                             16, 0, 0);
        }
#pragma unroll
        for (int it = 0; it < 2; ++it) {
            const int s = it * 8 + wave;
            const int n = s >> 1, ks = s & 1;
            const unsigned short* gv = Vth + (size_t)(n * 16 + l15) * Ss + t0 + ks * 32 + q4 * 8;
            __builtin_amdgcn_global_load_lds((const __attribute__((address_space(1))) unsigned int*)gv,
                                             (__attribute__((address_space(3))) unsigned int*)(VtS + (s * 64 + lane) * 8),
                                             16, 0, 0);
        }
        __syncthreads();

        if (t0 <= s0 + 15) {
            float sv[4][4];
#pragma unroll
            for (int g = 0; g < 4; ++g)
#pragma unroll
                for (int r = 0; r < 4; ++r) sv[g][r] = -1e30f;
#pragma unroll
            for (int g = 0; g < 4; ++g) {
                if (t0 + g * 16 <= s0 + 15) {
                    f32x4 scg = {};
#pragma unroll
                    for (int kc = 0; kc < 4; ++kc) {
                        short8 kf = *(const short8*)(Ks + ((g * 4 + kc) * 64 + lane) * 8);
                        scg = __builtin_amdgcn_mfma_f32_16x16x32_bf16(qf[kc], kf, scg, 0, 0, 0);
                    }
                    const int key = t0 + g * 16 + l15;
#pragma unroll
                    for (int r = 0; r < 4; ++r)
                        sv[g][r] = (key <= s0 + q4 * 4 + r) ? scg[r] : -1e30f;
                }
            }
            float mnew[4], alpha[4], sm[4];
            bool need = false;
#pragma unroll
            for (int r = 0; r < 4; ++r) {
                float mx = fmaxf(fmaxf(sv[0][r], sv[1][r]), fmaxf(sv[2][r], sv[3][r]));
#pragma unroll
                for (int off = 1; off < 16; off <<= 1)
                    mx = fmaxf(mx, __shfl_xor(mx, off, 16));
                mnew[r]  = fmaxf(m_i[r], mx);
                need = need || (mnew[r] > m_i[r]);
                alpha[r] = EXPFN(m_i[r] - mnew[r]);
                m_i[r] = mnew[r];
            }
            float p[4][4];
#pragma unroll
            for (int g = 0; g < 4; ++g)
#pragma unroll
                for (int r = 0; r < 4; ++r)
                    p[g][r] = EXPFN(sv[g][r] - mnew[r]);
#pragma unroll
            for (int r = 0; r < 4; ++r) {
                float s2 = (p[0][r] + p[1][r]) + (p[2][r] + p[3][r]);
#pragma unroll
                for (int off = 1; off < 16; off <<= 1)
                    s2 += __shfl_xor(s2, off, 16);
                sm[r] = s2;
            }
            if (__any(need)) {
#pragma unroll
                for (int r = 0; r < 4; ++r) l_i[r] *= alpha[r];
#pragma unroll
                for (int n = 0; n < 8; ++n)
#pragma unroll
                    for (int r = 0; r < 4; ++r)
                        o_acc[n][r] *= alpha[r];
            }
#pragma unroll
            for (int r = 0; r < 4; ++r) l_i[r] += sm[r];

            unsigned short* Pw = &Ps[wave][0];
#pragma unroll
            for (int g = 0; g < 4; ++g)
#pragma unroll
                for (int r = 0; r < 4; ++r)
                    Pw[(q4 * 4 + r) * 72 + g * 16 + l15] = f2bf(p[g][r]);

#pragma unroll
            for (int ks = 0; ks < 2; ++ks) {
                if (t0 + ks * 32 <= s0 + 15) {
                    short8 pfk = *(const short8*)(Pw + l15 * 72 + ks * 32 + q4 * 8);
#pragma unroll
                    for (int n = 0; n < 8; ++n) {
                        short8 vf = *(const short8*)(VtS + ((n * 2 + ks) * 64 + lane) * 8);
                        o_acc[n] = __builtin_amdgcn_mfma_f32_16x16x32_bf16(pfk, vf, o_acc[n], 0, 0, 0);
                    }
                }
            }
        }
        __syncthreads();
    }

    float inv[4];
#pragma unroll
    for (int r = 0; r < 4; ++r) inv[r] = 1.f / l_i[r];
#pragma unroll
    for (int n = 0; n < 8; ++n)
#pragma unroll
        for (int r = 0; r < 4; ++r) {
            const int query = s0 + q4 * 4 + r;
            AO[((size_t)(b * Ss + query)) * Hh + h * HDd + n * 16 + l15] = f2bf(o_acc[n][r] * inv[r]);
        }
}

// ---------------------------------------------------------------- host
extern "C" void kernel_launch(void* const* d_in, const int* in_sizes, int n_in,
                              void* d_out, int out_size, void* d_ws, size_t ws_size,
                              hipStream_t stream) {
    const float* X    = (const float*)d_in[0];
    const float* cosp = (const float*)d_in[1];
    const float* sinp = (const float*)d_in[2];
    const float* Wqkv = (const float*)d_in[3];
    const float* bqkv = (const float*)d_in[4];
    const float* Wout = (const float*)d_in[5];
    const float* bout = (const float*)d_in[6];
    float* out = (float*)d_out;

    char* ws = (char*)d_ws;
    size_t off = 0;
    auto carve = [&](size_t bytes) { void* p = ws + off; off += bytes; return p; };
    unsigned short* Xb    = (unsigned short*)carve((size_t)Mm * Hh * 2);        // 16 MB
    unsigned short* Wqkvb = (unsigned short*)carve((size_t)3 * Hh * Hh * 2);    // 24 MB
    unsigned short* Woutb = (unsigned short*)carve((size_t)Hh * Hh * 2);        //  8 MB
    unsigned short* QKVb  = (unsigned short*)carve((size_t)Mm * 3 * Hh * 2);    // 48 MB
    unsigned short* Qr    = (unsigned short*)carve((size_t)Mm * Hh * 2);        // 16 MB
    unsigned short* Kr    = (unsigned short*)carve((size_t)Mm * Hh * 2);        // 16 MB
    unsigned short* Vt    = (unsigned short*)carve((size_t)Mm * Hh * 2);        // 16 MB
    unsigned short* AOb   = (unsigned short*)carve((size_t)Mm * Hh * 2);        // 16 MB

    // 5 launches (was 7): cast3 -> gemm256 -> rope_v -> attn -> gemm_bt
    cast3<<<24576, 256, 0, stream>>>(X, Xb, Wqkv, Wqkvb, Wout, Woutb);

    gemm256<unsigned short><<<dim3((3 * Hh) / 256, Mm / 256), 512, 0, stream>>>(
        Xb, Wqkvb, bqkv, QKVb, Mm, 3 * Hh, Hh);

    rope_v<<<6144, 256, 0, stream>>>(QKVb, cosp, sinp, Qr, Kr, Vt);

    attn_fwd<<<dim3(Ss / 128, Bb * NHh), 512, 0, stream>>>(Qr, Kr, Vt, AOb);

    gemm_bt<float><<<dim3(Hh / 128, Mm / 128), 256, 0, stream>>>(
        AOb, Woutb, bout, out, Mm, Hh, Hh);
}